// Round 4
// baseline (188.086 us; speedup 1.0000x reference)
//
#include <hip/hip_runtime.h>
#include <hip/hip_fp16.h>

#define P_PLANE (1080*1920)          // 2,073,600 pixels per channel plane
#define LUT_C   35937                 // 33*33*33, per-channel LUT stride
#define N_IMG   4
#define SMEM_WORDS 35937
#define SMEM_BYTES (SMEM_WORDS * 4)   // 143,748 B of LDS
#define QPI (P_PLANE / 4)             // 518,400 quads per image
#define TOTAL_Q (N_IMG * QPI)         // 2,073,600 quads
#define NBLK 256
#define NTHR 1024
#define JPT 8                          // quads per thread (256*1024*8 >= TOTAL_Q)

typedef float fvec4 __attribute__((ext_vector_type(4)));   // builtin-compatible float4

// ---------------------------------------------------------------------------
// Build linear u8 table in ws: entry i (= b*1089+g*33+r) packs (r,g,b,0) u8.
// ---------------------------------------------------------------------------
__global__ __launch_bounds__(256) void build_lin_u8(const float* __restrict__ lut,
                                                    unsigned int* __restrict__ T) {
    int i = blockIdx.x * blockDim.x + threadIdx.x;
    if (i >= LUT_C) return;
    unsigned int r = (unsigned int)__float2int_rn(lut[i] * 255.0f);
    unsigned int g = (unsigned int)__float2int_rn(lut[LUT_C + i] * 255.0f);
    unsigned int b = (unsigned int)__float2int_rn(lut[2 * LUT_C + i] * 255.0f);
    T[i] = r | (g << 8) | (b << 16);
}

__device__ __forceinline__ float ub0(unsigned int e) { return (float)(e & 255u); }
__device__ __forceinline__ float ub1(unsigned int e) { return (float)((e >> 8) & 255u); }
__device__ __forceinline__ float ub2(unsigned int e) { return (float)((e >> 16) & 255u); }

__device__ __forceinline__ size_t quad_base(int q) {
    int n  = q / QPI;                     // magic-mul division
    int p4 = q - n * QPI;
    return (size_t)n * 3 * P_PLANE + (size_t)p4 * 4;
}

// Process one quad (4 px) from registers + LDS table; nontemporal store.
__device__ __forceinline__ void process_quad(const unsigned int* s_lut,
                                             fvec4 r4, fvec4 g4, fvec4 b4,
                                             float* out, size_t base) {
    const float inv = (float)(1.0 / (1.000001 / 32.0));   // matches reference f32 rounding
    const float qs = 1.0f / 255.0f;
    fvec4 vR, vG, vB;
#pragma unroll
    for (int i = 0; i < 4; ++i) {
        float tr = r4[i] * inv;
        float tg = g4[i] * inv;
        float tb = b4[i] * inv;
        float fr_ = floorf(tr), fg_ = floorf(tg), fb_ = floorf(tb);
        float fr = tr - fr_, fg = tg - fg_, fb = tb - fb_;  // fracs BEFORE clip (ref semantics)
        int ri = min(max((int)fr_, 0), 31);
        int gi = min(max((int)fg_, 0), 31);
        int bi = min(max((int)fb_, 0), 31);
        int idx = bi * 1089 + gi * 33 + ri;

        unsigned int e000 = s_lut[idx],        e001 = s_lut[idx + 1];
        unsigned int e010 = s_lut[idx + 33],   e011 = s_lut[idx + 34];
        unsigned int e100 = s_lut[idx + 1089], e101 = s_lut[idx + 1090];
        unsigned int e110 = s_lut[idx + 1122], e111 = s_lut[idx + 1123];

        float wr1 = fr, wr0 = 1.0f - fr;
        float wg1 = fg, wg0 = 1.0f - fg;
        float wb1 = fb * qs, wb0 = (1.0f - fb) * qs;       // fold 1/255 here
        float w00 = wb0 * wg0, w01 = wb0 * wg1, w10 = wb1 * wg0, w11 = wb1 * wg1;
        float w000 = w00 * wr0, w001 = w00 * wr1;
        float w010 = w01 * wr0, w011 = w01 * wr1;
        float w100 = w10 * wr0, w101 = w10 * wr1;
        float w110 = w11 * wr0, w111 = w11 * wr1;

        float aR, aG, aB;
        aR = w000 * ub0(e000);            aG = w000 * ub1(e000);            aB = w000 * ub2(e000);
        aR = fmaf(w001, ub0(e001), aR);   aG = fmaf(w001, ub1(e001), aG);   aB = fmaf(w001, ub2(e001), aB);
        aR = fmaf(w010, ub0(e010), aR);   aG = fmaf(w010, ub1(e010), aG);   aB = fmaf(w010, ub2(e010), aB);
        aR = fmaf(w011, ub0(e011), aR);   aG = fmaf(w011, ub1(e011), aG);   aB = fmaf(w011, ub2(e011), aB);
        aR = fmaf(w100, ub0(e100), aR);   aG = fmaf(w100, ub1(e100), aG);   aB = fmaf(w100, ub2(e100), aB);
        aR = fmaf(w101, ub0(e101), aR);   aG = fmaf(w101, ub1(e101), aG);   aB = fmaf(w101, ub2(e101), aB);
        aR = fmaf(w110, ub0(e110), aR);   aG = fmaf(w110, ub1(e110), aG);   aB = fmaf(w110, ub2(e110), aB);
        aR = fmaf(w111, ub0(e111), aR);   aG = fmaf(w111, ub1(e111), aG);   aB = fmaf(w111, ub2(e111), aB);

        vR[i] = aR; vG[i] = aG; vB[i] = aB;
    }
    __builtin_nontemporal_store(vR, (fvec4*)(out + base));
    __builtin_nontemporal_store(vG, (fvec4*)(out + base + P_PLANE));
    __builtin_nontemporal_store(vB, (fvec4*)(out + base + 2 * P_PLANE));
}

// ---------------------------------------------------------------------------
// Main kernel: full LUT (u8x4) in LDS; JPT strided quads per thread with a
// register double-buffer (prefetch quad j+1 while computing quad j).
// ---------------------------------------------------------------------------
__global__ __launch_bounds__(NTHR) void apply_lut_lds(const float* __restrict__ x,
                                                      const unsigned int* __restrict__ T,
                                                      float* __restrict__ out) {
    extern __shared__ unsigned int s_lut[];
    const int tid = threadIdx.x;

    // Fill LDS: 8984 uint4 + 1 tail word, coalesced.
    {
        const uint4* Tv = (const uint4*)T;
        uint4* sv = (uint4*)s_lut;
        for (int i = tid; i < SMEM_WORDS / 4; i += NTHR) sv[i] = Tv[i];
        if (tid == 0) s_lut[SMEM_WORDS - 1] = T[SMEM_WORDS - 1];
    }
    __syncthreads();

    const int NT = NBLK * NTHR;                 // stride between a thread's quads
    const int q0 = blockIdx.x * NTHR + tid;

    fvec4 R, G, B, Rn, Gn, Bn;
    size_t base = quad_base(q0), basen = 0;
    // j=0 always valid (q0 < NT <= TOTAL_Q)
    R = *(const fvec4*)(x + base);
    G = *(const fvec4*)(x + base + P_PLANE);
    B = *(const fvec4*)(x + base + 2 * P_PLANE);

#pragma unroll
    for (int j = 0; j < JPT; ++j) {
        if (j + 1 < JPT) {                       // prefetch next quad
            int qn = q0 + (j + 1) * NT;
            if (qn < TOTAL_Q) {
                basen = quad_base(qn);
                Rn = *(const fvec4*)(x + basen);
                Gn = *(const fvec4*)(x + basen + P_PLANE);
                Bn = *(const fvec4*)(x + basen + 2 * P_PLANE);
            }
        }
        int qc = q0 + j * NT;
        if (qc < TOTAL_Q)
            process_quad(s_lut, R, G, B, out, base);
        base = basen; R = Rn; G = Gn; B = Bn;
    }
}

// ===========================================================================
// Fallback path (R0, proven): fp16 cell-duplicated table + global gathers.
// ===========================================================================
__global__ __launch_bounds__(256) void build_table(const float* __restrict__ lut,
                                                   uint4* __restrict__ T) {
    int cell = blockIdx.x * blockDim.x + threadIdx.x;   // 0 .. 32767
    int rid = cell & 31;
    int gid = (cell >> 5) & 31;
    int bid = cell >> 10;
    const float* b0 = lut + bid * 1089 + gid * 33 + rid;
    uint4 q[4];
    __half* h = (__half*)q;
#pragma unroll
    for (int k = 0; k < 8; ++k) {
        int off = (k >> 2) * 1089 + ((k >> 1) & 1) * 33 + (k & 1);
        h[k * 4 + 0] = __float2half(b0[off]);
        h[k * 4 + 1] = __float2half(b0[LUT_C + off]);
        h[k * 4 + 2] = __float2half(b0[2 * LUT_C + off]);
        h[k * 4 + 3] = __float2half(0.0f);
    }
    uint4* dst = T + (size_t)cell * 4;
    dst[0] = q[0]; dst[1] = q[1]; dst[2] = q[2]; dst[3] = q[3];
}

__device__ __forceinline__ void acc_chunk(const uint4& q, float wA, float wB,
                                          float& aR, float& aG, float& aB) {
    const __half* h = (const __half*)&q;
    aR = fmaf(wA, __half2float(h[0]), fmaf(wB, __half2float(h[4]), aR));
    aG = fmaf(wA, __half2float(h[1]), fmaf(wB, __half2float(h[5]), aG));
    aB = fmaf(wA, __half2float(h[2]), fmaf(wB, __half2float(h[6]), aB));
}

__global__ __launch_bounds__(256) void apply_lut(const float* __restrict__ x,
                                                 const __half* __restrict__ T,
                                                 float* __restrict__ out) {
    const float inv = (float)(1.0 / (1.000001 / 32.0));
    int n  = blockIdx.y;
    int i4 = blockIdx.x * blockDim.x + threadIdx.x;
    size_t base = (size_t)n * 3 * P_PLANE + (size_t)i4 * 4;

    float4 r4 = *(const float4*)(x + base);
    float4 g4 = *(const float4*)(x + base + P_PLANE);
    float4 b4 = *(const float4*)(x + base + 2 * P_PLANE);

    float r[4] = {r4.x, r4.y, r4.z, r4.w};
    float g[4] = {g4.x, g4.y, g4.z, g4.w};
    float b[4] = {b4.x, b4.y, b4.z, b4.w};
    float oR[4], oG[4], oB[4];

#pragma unroll
    for (int i = 0; i < 4; ++i) {
        float tr = r[i] * inv;
        float tg = g[i] * inv;
        float tb = b[i] * inv;
        float fr_ = floorf(tr), fg_ = floorf(tg), fb_ = floorf(tb);
        float fr = tr - fr_, fg = tg - fg_, fb = tb - fb_;
        int ri = min(max((int)fr_, 0), 31);
        int gi = min(max((int)fg_, 0), 31);
        int bi = min(max((int)fb_, 0), 31);

        const uint4* cp = (const uint4*)(T + ((size_t)(((bi << 5) | gi) << 5 | ri) << 5));
        uint4 q0 = cp[0], q1 = cp[1], q2 = cp[2], q3 = cp[3];

        float wr1 = fr, wr0 = 1.0f - fr;
        float wg1 = fg, wg0 = 1.0f - fg;
        float wb1 = fb, wb0 = 1.0f - fb;
        float w00 = wb0 * wg0, w01 = wb0 * wg1, w10 = wb1 * wg0, w11 = wb1 * wg1;

        float aR = 0.f, aG = 0.f, aB = 0.f;
        acc_chunk(q0, w00 * wr0, w00 * wr1, aR, aG, aB);
        acc_chunk(q1, w01 * wr0, w01 * wr1, aR, aG, aB);
        acc_chunk(q2, w10 * wr0, w10 * wr1, aR, aG, aB);
        acc_chunk(q3, w11 * wr0, w11 * wr1, aR, aG, aB);

        oR[i] = aR; oG[i] = aG; oB[i] = aB;
    }

    *(float4*)(out + base)               = make_float4(oR[0], oR[1], oR[2], oR[3]);
    *(float4*)(out + base + P_PLANE)     = make_float4(oG[0], oG[1], oG[2], oG[3]);
    *(float4*)(out + base + 2 * P_PLANE) = make_float4(oB[0], oB[1], oB[2], oB[3]);
}

extern "C" void kernel_launch(void* const* d_in, const int* in_sizes, int n_in,
                              void* d_out, int out_size, void* d_ws, size_t ws_size,
                              hipStream_t stream) {
    const float* lut = (const float*)d_in[0];
    const float* x   = (const float*)d_in[1];
    float* out = (float*)d_out;

    int dev = 0;
    (void)hipGetDevice(&dev);
    int max_shm = 0;
    (void)hipDeviceGetAttribute(&max_shm, hipDeviceAttributeMaxSharedMemoryPerBlock, dev);
    static_assert(SMEM_BYTES == 143748, "lut lds size");
    (void)hipFuncSetAttribute((const void*)apply_lut_lds,
                              hipFuncAttributeMaxDynamicSharedMemorySize, SMEM_BYTES);

    if (max_shm >= SMEM_BYTES && ws_size >= (size_t)SMEM_BYTES) {
        unsigned int* T = (unsigned int*)d_ws;
        build_lin_u8<<<(LUT_C + 255) / 256, 256, 0, stream>>>(lut, T);
        apply_lut_lds<<<NBLK, NTHR, SMEM_BYTES, stream>>>(x, T, out);
    } else {
        __half* T = (__half*)d_ws;
        build_table<<<128, 256, 0, stream>>>(lut, (uint4*)T);
        apply_lut<<<dim3(P_PLANE / (4 * 256), N_IMG), 256, 0, stream>>>(x, T, out);
    }
}